// Round 1
// baseline (608.166 us; speedup 1.0000x reference)
//
#include <hip/hip_runtime.h>
#include <cstddef>

// Problem constants (match reference)
constexpr int B = 64, T = 1024, I = 8, H = 512, O = 2;
constexpr float ALPHA = 0.2f;
constexpr float NOISE_STD = 0.05f;

// Software-pipeline depth for the d-buffer loads in the RNN kernel.
// 8 steps x ~240 issue-cycles/step ~= 1900 cyc of overlap > ~900 cyc HBM latency.
constexpr int PF = 8;

// ---------------------------------------------------------------------------
// DPP wave-64 sum reduction: result (total of all 64 lanes) lands in lane 63.
// All-VALU (no LDS crossbar): 6 dependent v_add_f32_dpp, ~5 cyc each.
// ---------------------------------------------------------------------------
template <int CTRL>
__device__ __forceinline__ float dpp_add(float x) {
    int y = __builtin_amdgcn_update_dpp(0, __float_as_int(x), CTRL, 0xF, 0xF, true);
    return x + __int_as_float(y);
}

__device__ __forceinline__ float wave_sum_to_lane63(float x) {
    x = dpp_add<0x111>(x);  // row_shr:1
    x = dpp_add<0x112>(x);  // row_shr:2
    x = dpp_add<0x114>(x);  // row_shr:4
    x = dpp_add<0x118>(x);  // row_shr:8   -> lane 15 of each row = row sum
    x = dpp_add<0x142>(x);  // row_bcast:15
    x = dpp_add<0x143>(x);  // row_bcast:31 -> lane 63 = full sum
    return x;
}

__device__ __forceinline__ float bcast63(float x) {
    return __int_as_float(__builtin_amdgcn_readlane(__float_as_int(x), 63));
}

// Fast tanh: 1 - 2/(exp(2x)+1), via v_exp_f32 + v_rcp_f32.
// Saturates correctly: x->+inf => exp2->inf => 1; x->-inf => exp2->0 => -1.
__device__ __forceinline__ float fast_tanh(float x) {
    float z = __builtin_amdgcn_exp2f(x * 2.885390081777927f);  // e^(2x)
    return fmaf(-2.0f, __builtin_amdgcn_rcpf(z + 1.0f), 1.0f);
}

// ---------------------------------------------------------------------------
// Kernel 1: d[b,t,h] = NOISE_STD*noise + ALPHA*(input @ (wi*si))
// One block per (b,t) row: the 8 input values are blockIdx-uniform => scalar
// loads; each of 128 threads handles one float4 of H. Pure memory-bound.
// ---------------------------------------------------------------------------
__global__ __launch_bounds__(128)
void precompute_d_kernel(const float* __restrict__ input,
                         const float* __restrict__ noise,
                         const float* __restrict__ wi,
                         const float* __restrict__ si,
                         float* __restrict__ d) {
    const int    bt = blockIdx.x;           // 0 .. B*T-1
    const int    hq = threadIdx.x << 2;     // float4 offset within H

    float x[I];
#pragma unroll
    for (int i = 0; i < I; ++i) x[i] = input[(size_t)bt * I + i] * si[i];

    const size_t off = (size_t)bt * H + hq;
    const float4 nz  = *(const float4*)(noise + off);

    float4 p = make_float4(0.f, 0.f, 0.f, 0.f);
#pragma unroll
    for (int i = 0; i < I; ++i) {
        const float4 w = *(const float4*)(wi + i * H + hq);
        p.x = fmaf(x[i], w.x, p.x);
        p.y = fmaf(x[i], w.y, p.y);
        p.z = fmaf(x[i], w.z, p.z);
        p.w = fmaf(x[i], w.w, p.w);
    }
    float4 o;
    o.x = fmaf(NOISE_STD, nz.x, ALPHA * p.x);
    o.y = fmaf(NOISE_STD, nz.y, ALPHA * p.y);
    o.z = fmaf(NOISE_STD, nz.z, ALPHA * p.z);
    o.w = fmaf(NOISE_STD, nz.w, ALPHA * p.w);
    *(float4*)(d + off) = o;
}

// ---------------------------------------------------------------------------
// Kernel 2: sequential RNN. One wave per batch element. Lane l owns hidden
// units j = 256*k + 4*l + c (k in {0,1}, c in {0..3}) => two coalesced
// float4 slots per lane. DPP reductions, fast tanh, SGPR broadcast.
// NEW: PF-deep register ring buffer for the d loads (statically indexed via
// an 8x-unrolled inner loop) so HBM latency (~900 cyc) is fully hidden behind
// ~8 steps of issue (~1900 cyc). Previous version prefetched only 1 step deep
// and stalled ~650 cyc/step on s_waitcnt vmcnt.
// ---------------------------------------------------------------------------
template <bool FUSED>
__global__ __launch_bounds__(64)
void rnn_kernel(const float* __restrict__ dbuf,   // !FUSED: precomputed d ; FUSED: noise
                const float* __restrict__ input,  // FUSED only
                const float* __restrict__ wi,     // FUSED only
                const float* __restrict__ si,     // FUSED only
                const float* __restrict__ m,
                const float* __restrict__ n,
                const float* __restrict__ wo,
                const float* __restrict__ so,
                const float* __restrict__ h0,
                float* __restrict__ out,          // (B,T,O)
                float* __restrict__ traj)         // (B,T,H)
{
    const int b    = blockIdx.x;
    const int lane = threadIdx.x;   // 0..63

    constexpr float RS  = ALPHA / (float)H;   // scale for recurrent term
    constexpr float OMA = 1.0f - ALPHA;

    const float so0 = so[0] / (float)H;
    const float so1 = so[1] / (float)H;

    float m0s[8], m1s[8], n0[8], n1[8], wo0s[8], wo1s[8], h[8], r[8];
    float wif[I][8];  // only used when FUSED

#pragma unroll
    for (int k = 0; k < 2; ++k) {
#pragma unroll
        for (int c = 0; c < 4; ++c) {
            const int s = k * 4 + c;
            const int j = 256 * k + 4 * lane + c;
            m0s[s]  = m[2 * j + 0] * RS;
            m1s[s]  = m[2 * j + 1] * RS;
            n0[s]   = n[2 * j + 0];
            n1[s]   = n[2 * j + 1];
            wo0s[s] = wo[2 * j + 0] * so0;
            wo1s[s] = wo[2 * j + 1] * so1;
            h[s]    = h0[j];
            r[s]    = tanhf(h[s]);   // once, outside the hot loop: full precision
            if (FUSED) {
#pragma unroll
                for (int i = 0; i < I; ++i) wif[i][s] = wi[i * H + j] * si[i];
            }
        }
    }

    const float* pd    = dbuf + (size_t)b * T * H + 4 * lane;
    float*       ptraj = traj + (size_t)b * T * H + 4 * lane;
    const float* pin   = input + (size_t)b * T * I;  // FUSED only
    float*       pout  = out + (size_t)b * T * O;

    // ---- PF-deep software pipeline prologue: fill the register ring ----
    float4 buf0[PF], buf1[PF];
#pragma unroll
    for (int u = 0; u < PF; ++u) {
        buf0[u] = *(const float4*)(pd + (size_t)u * H);
        buf1[u] = *(const float4*)(pd + (size_t)u * H + 256);
    }

    static_assert(T % PF == 0, "T must be a multiple of PF");

    for (int tb = 0; tb < T; tb += PF) {
#pragma unroll
        for (int u = 0; u < PF; ++u) {
            const int t = tb + u;

            // ---- consume ring slot u (data for step t), then refill it with
            //      step t+PF. Static index u => stays in registers. ----
            const float4 cur0 = buf0[u];
            const float4 cur1 = buf1[u];
            if (t + PF < T) {
                buf0[u] = *(const float4*)(pd + (size_t)(t + PF) * H);
                buf1[u] = *(const float4*)(pd + (size_t)(t + PF) * H + 256);
            }

            // ---- 4 dot products of r: a0,a1 (recurrence) + o0,o1 (output) ----
            // 2-way split accumulators halve the dependent fma chain.
            float pa0a = 0.f, pa1a = 0.f, po0a = 0.f, po1a = 0.f;
            float pa0b = 0.f, pa1b = 0.f, po0b = 0.f, po1b = 0.f;
#pragma unroll
            for (int s = 0; s < 4; ++s) {
                pa0a = fmaf(r[s], n0[s], pa0a);
                pa1a = fmaf(r[s], n1[s], pa1a);
                po0a = fmaf(r[s], wo0s[s], po0a);
                po1a = fmaf(r[s], wo1s[s], po1a);
                pa0b = fmaf(r[s + 4], n0[s + 4], pa0b);
                pa1b = fmaf(r[s + 4], n1[s + 4], pa1b);
                po0b = fmaf(r[s + 4], wo0s[s + 4], po0b);
                po1b = fmaf(r[s + 4], wo1s[s + 4], po1b);
            }
            float ra0 = wave_sum_to_lane63(pa0a + pa0b);
            float ra1 = wave_sum_to_lane63(pa1a + pa1b);
            float ro0 = wave_sum_to_lane63(po0a + po0b);
            float ro1 = wave_sum_to_lane63(po1a + po1b);

            // ---- d values for this step; pre[] = (1-a)*h + d hoisted off the
            //      post-broadcast critical path (overlaps the DPP chain) ----
            float dv[8];
            if (!FUSED) {
                dv[0] = cur0.x; dv[1] = cur0.y; dv[2] = cur0.z; dv[3] = cur0.w;
                dv[4] = cur1.x; dv[5] = cur1.y; dv[6] = cur1.z; dv[7] = cur1.w;
            } else {
                float x[I];
#pragma unroll
                for (int i = 0; i < I; ++i) x[i] = pin[(size_t)t * I + i];
                const float nzv[8] = {cur0.x, cur0.y, cur0.z, cur0.w,
                                      cur1.x, cur1.y, cur1.z, cur1.w};
#pragma unroll
                for (int s = 0; s < 8; ++s) {
                    float p = 0.f;
#pragma unroll
                    for (int i = 0; i < I; ++i) p = fmaf(x[i], wif[i][s], p);
                    dv[s] = fmaf(NOISE_STD, nzv[s], ALPHA * p);
                }
            }
            float pre[8];
#pragma unroll
            for (int s = 0; s < 8; ++s) pre[s] = fmaf(h[s], OMA, dv[s]);

            if (lane == 63 && t > 0) {
                *(float2*)(pout + (size_t)(t - 1) * O) = make_float2(ro0, ro1);
            }

            const float a0 = bcast63(ra0);   // SGPR broadcast, free in fma
            const float a1 = bcast63(ra1);

            // ---- state update + fast tanh (2 fma + tanh post-broadcast) ----
#pragma unroll
            for (int s = 0; s < 8; ++s) {
                h[s] = fmaf(a1, m1s[s], fmaf(a0, m0s[s], pre[s]));
                r[s] = fast_tanh(h[s]);
            }

            // ---- store trajectory (h post-update) ----
            *(float4*)(ptraj + (size_t)t * H + 0)   = make_float4(h[0], h[1], h[2], h[3]);
            *(float4*)(ptraj + (size_t)t * H + 256) = make_float4(h[4], h[5], h[6], h[7]);
        }
    }

    // ---- final output for t = T-1 (uses r_{T-1}) ----
    float po0 = 0.f, po1 = 0.f;
#pragma unroll
    for (int s = 0; s < 8; ++s) {
        po0 = fmaf(r[s], wo0s[s], po0);
        po1 = fmaf(r[s], wo1s[s], po1);
    }
    po0 = wave_sum_to_lane63(po0);
    po1 = wave_sum_to_lane63(po1);
    if (lane == 63) {
        *(float2*)(pout + (size_t)(T - 1) * O) = make_float2(po0, po1);
    }
}

// ---------------------------------------------------------------------------
extern "C" void kernel_launch(void* const* d_in, const int* in_sizes, int n_in,
                              void* d_out, int out_size, void* d_ws, size_t ws_size,
                              hipStream_t stream) {
    const float* input = (const float*)d_in[0];
    const float* noise = (const float*)d_in[1];
    const float* wi    = (const float*)d_in[2];
    const float* si    = (const float*)d_in[3];
    const float* m     = (const float*)d_in[4];
    const float* n     = (const float*)d_in[5];
    const float* wo    = (const float*)d_in[6];
    const float* so    = (const float*)d_in[7];
    const float* h0    = (const float*)d_in[8];

    float* out  = (float*)d_out;                       // (B,T,O) first
    float* traj = (float*)d_out + (size_t)B * T * O;   // then (B,T,H)

    const size_t d_bytes = (size_t)B * T * H * sizeof(float);

    if (ws_size >= d_bytes) {
        float* dbuf = (float*)d_ws;
        // 1) precompute d — one block per (b,t) row
        precompute_d_kernel<<<B * T, 128, 0, stream>>>(input, noise, wi, si, dbuf);
        // 2) sequential RNN, one wave per batch
        rnn_kernel<false><<<B, 64, 0, stream>>>(dbuf, nullptr, nullptr, nullptr,
                                                m, n, wo, so, h0, out, traj);
    } else {
        // fallback: fuse input projection into the RNN kernel
        rnn_kernel<true><<<B, 64, 0, stream>>>(noise, input, wi, si,
                                               m, n, wo, so, h0, out, traj);
    }
}

// Round 2
// 587.344 us; speedup vs baseline: 1.0355x; 1.0355x over previous
//
#include <hip/hip_runtime.h>
#include <cstddef>

// Problem constants (match reference)
constexpr int B = 64, T = 1024, I = 8, H = 512, O = 2;
constexpr float ALPHA = 0.2f;
constexpr float NOISE_STD = 0.05f;

// Ring depth for the d-buffer software pipeline (float2 per lane per step).
constexpr int PF = 8;

// ---------------------------------------------------------------------------
// DPP wave-64 sum reduction: result (total of all 64 lanes) lands in lane 63.
// ---------------------------------------------------------------------------
template <int CTRL>
__device__ __forceinline__ float dpp_add(float x) {
    int y = __builtin_amdgcn_update_dpp(0, __float_as_int(x), CTRL, 0xF, 0xF, true);
    return x + __int_as_float(y);
}

__device__ __forceinline__ float wave_sum_to_lane63(float x) {
    x = dpp_add<0x111>(x);  // row_shr:1
    x = dpp_add<0x112>(x);  // row_shr:2
    x = dpp_add<0x114>(x);  // row_shr:4
    x = dpp_add<0x118>(x);  // row_shr:8   -> lane 15 of each row = row sum
    x = dpp_add<0x142>(x);  // row_bcast:15
    x = dpp_add<0x143>(x);  // row_bcast:31 -> lane 63 = full sum
    return x;
}

__device__ __forceinline__ float bcast63(float x) {
    return __int_as_float(__builtin_amdgcn_readlane(__float_as_int(x), 63));
}

// Fast tanh: 1 - 2/(exp(2x)+1), via v_exp_f32 + v_rcp_f32.
__device__ __forceinline__ float fast_tanh(float x) {
    float z = __builtin_amdgcn_exp2f(x * 2.885390081777927f);  // e^(2x)
    return fmaf(-2.0f, __builtin_amdgcn_rcpf(z + 1.0f), 1.0f);
}

// ---------------------------------------------------------------------------
// Kernel 1: d[b,t,h] = NOISE_STD*noise + ALPHA*(input @ (wi*si))
// ---------------------------------------------------------------------------
__global__ __launch_bounds__(128)
void precompute_d_kernel(const float* __restrict__ input,
                         const float* __restrict__ noise,
                         const float* __restrict__ wi,
                         const float* __restrict__ si,
                         float* __restrict__ d) {
    const int    bt = blockIdx.x;           // 0 .. B*T-1
    const int    hq = threadIdx.x << 2;     // float4 offset within H

    float x[I];
#pragma unroll
    for (int i = 0; i < I; ++i) x[i] = input[(size_t)bt * I + i] * si[i];

    const size_t off = (size_t)bt * H + hq;
    const float4 nz  = *(const float4*)(noise + off);

    float4 p = make_float4(0.f, 0.f, 0.f, 0.f);
#pragma unroll
    for (int i = 0; i < I; ++i) {
        const float4 w = *(const float4*)(wi + i * H + hq);
        p.x = fmaf(x[i], w.x, p.x);
        p.y = fmaf(x[i], w.y, p.y);
        p.z = fmaf(x[i], w.z, p.z);
        p.w = fmaf(x[i], w.w, p.w);
    }
    float4 o;
    o.x = fmaf(NOISE_STD, nz.x, ALPHA * p.x);
    o.y = fmaf(NOISE_STD, nz.y, ALPHA * p.y);
    o.z = fmaf(NOISE_STD, nz.z, ALPHA * p.z);
    o.w = fmaf(NOISE_STD, nz.w, ALPHA * p.w);
    *(float4*)(d + off) = o;
}

// ---------------------------------------------------------------------------
// Kernel 2 (NEW): sequential RNN split across 4 waves per batch.
// 256 threads/block, block b = batch b. Wave w (0..3) owns hidden units
// [w*128, w*128+128); lane l owns units j0 = w*128 + 2*l and j0+1 (float2
// coalesced). Per step: each wave DPP-reduces its 128-unit partial of the
// rank-2 projection a = r@n, lane63 writes a float2 to a double-buffered LDS
// slot, ONE barrier, all lanes re-read the 4 partials (broadcast) and finish.
// Race-free with one barrier: each wave consumes its LDS read (into h/r)
// before its next ds_write in program order, so by the time any wave passes
// barrier(t+1), all reads of buffer (t&1) are complete.
// Output dots (r@wo) are NOT computed here — deferred to out_kernel (traj
// holds everything needed), removing 16 fma + 12 DPP from the serial loop.
// ---------------------------------------------------------------------------
__global__ __launch_bounds__(256)
void rnn4_kernel(const float* __restrict__ dbuf,
                 const float* __restrict__ m,
                 const float* __restrict__ n,
                 const float* __restrict__ h0,
                 float* __restrict__ traj)         // (B,T,H)
{
    const int b    = blockIdx.x;
    const int w    = threadIdx.x >> 6;
    const int lane = threadIdx.x & 63;
    const int j0   = w * 128 + 2 * lane;   // first of this lane's 2 units

    constexpr float RS  = ALPHA / (float)H;
    constexpr float OMA = 1.0f - ALPHA;

    // Coefficients for 2 adjacent units: m/n rows 2*j0 .. 2*j0+3 (16B aligned)
    const float4 mv = *(const float4*)(m + 2 * j0);
    const float4 nv = *(const float4*)(n + 2 * j0);
    const float mm0[2] = {mv.x * RS, mv.z * RS};
    const float mm1[2] = {mv.y * RS, mv.w * RS};
    const float nn0[2] = {nv.x, nv.z};
    const float nn1[2] = {nv.y, nv.w};

    const float2 h0v = *(const float2*)(h0 + j0);
    float h[2] = {h0v.x, h0v.y};
    float r[2] = {tanhf(h[0]), tanhf(h[1])};

    __shared__ float2 part[2][4];   // [t&1][wave]

    const float* pd = dbuf + (size_t)b * T * H + j0;
    float*       pt = traj + (size_t)b * T * H + j0;

    // ---- fill the PF-deep register ring (statically indexed) ----
    float2 ring[PF];
#pragma unroll
    for (int u = 0; u < PF; ++u) ring[u] = *(const float2*)(pd + (size_t)u * H);

    static_assert(T % PF == 0, "T must be a multiple of PF");

    for (int tb = 0; tb < T; tb += PF) {
#pragma unroll
        for (int u = 0; u < PF; ++u) {
            const int t = tb + u;

            const float2 d = ring[u];
            if (t + PF < T) ring[u] = *(const float2*)(pd + (size_t)(t + PF) * H);

            // per-wave partial of a = r @ n (2 values)
            float pa0 = fmaf(r[1], nn0[1], r[0] * nn0[0]);
            float pa1 = fmaf(r[1], nn1[1], r[0] * nn1[0]);
            pa0 = wave_sum_to_lane63(pa0);
            pa1 = wave_sum_to_lane63(pa1);
            if (lane == 63) part[t & 1][w] = make_float2(pa0, pa1);

            // off-critical-path: (1-a)*h + d while the barrier settles
            const float pre0 = fmaf(h[0], OMA, d.x);
            const float pre1 = fmaf(h[1], OMA, d.y);

            __syncthreads();

            // broadcast-read all 4 wave partials (same addr across lanes)
            const float4 q0 = *(const float4*)&part[t & 1][0];  // waves 0,1
            const float4 q1 = *(const float4*)&part[t & 1][2];  // waves 2,3
            const float a0 = (q0.x + q0.z) + (q1.x + q1.z);
            const float a1 = (q0.y + q0.w) + (q1.y + q1.w);

            h[0] = fmaf(a1, mm1[0], fmaf(a0, mm0[0], pre0));
            h[1] = fmaf(a1, mm1[1], fmaf(a0, mm0[1], pre1));
            r[0] = fast_tanh(h[0]);
            r[1] = fast_tanh(h[1]);

            *(float2*)(pt + (size_t)t * H) = make_float2(h[0], h[1]);
        }
    }
}

// ---------------------------------------------------------------------------
// Kernel 3 (NEW): out[b,t,:] = tanh(traj[b,t,:]) @ (wo*so) / H.
// Massively parallel over (b,t); traj is L3-warm right after rnn4. One wave
// per (b,t) row, 4 rows per 256-thread block.
// ---------------------------------------------------------------------------
__global__ __launch_bounds__(256)
void out_kernel(const float* __restrict__ traj,
                const float* __restrict__ wo,
                const float* __restrict__ so,
                float* __restrict__ out) {
    const int bt   = blockIdx.x * 4 + (threadIdx.x >> 6);
    const int lane = threadIdx.x & 63;

    const float so0 = so[0] / (float)H;
    const float so1 = so[1] / (float)H;

    const float* pt = traj + (size_t)bt * H;

    float o0 = 0.f, o1 = 0.f;
#pragma unroll
    for (int k = 0; k < 2; ++k) {
        const int j = 256 * k + 4 * lane;
        const float4 hv = *(const float4*)(pt + j);
        const float4 w0 = *(const float4*)(wo + 2 * j);      // units j, j+1
        const float4 w1 = *(const float4*)(wo + 2 * j + 4);  // units j+2, j+3
        const float r0 = fast_tanh(hv.x);
        const float r1 = fast_tanh(hv.y);
        const float r2 = fast_tanh(hv.z);
        const float r3 = fast_tanh(hv.w);
        o0 = fmaf(r0, w0.x, o0); o1 = fmaf(r0, w0.y, o1);
        o0 = fmaf(r1, w0.z, o0); o1 = fmaf(r1, w0.w, o1);
        o0 = fmaf(r2, w1.x, o0); o1 = fmaf(r2, w1.y, o1);
        o0 = fmaf(r3, w1.z, o0); o1 = fmaf(r3, w1.w, o1);
    }
    o0 = wave_sum_to_lane63(o0);
    o1 = wave_sum_to_lane63(o1);
    if (lane == 63) {
        *(float2*)(out + (size_t)bt * O) = make_float2(o0 * so0, o1 * so1);
    }
}

// ---------------------------------------------------------------------------
// Fallback (no workspace): original single-wave fused kernel, computes
// everything including outputs.
// ---------------------------------------------------------------------------
__global__ __launch_bounds__(64)
void rnn_fused_kernel(const float* __restrict__ noise,
                      const float* __restrict__ input,
                      const float* __restrict__ wi,
                      const float* __restrict__ si,
                      const float* __restrict__ m,
                      const float* __restrict__ n,
                      const float* __restrict__ wo,
                      const float* __restrict__ so,
                      const float* __restrict__ h0,
                      float* __restrict__ out,
                      float* __restrict__ traj)
{
    const int b    = blockIdx.x;
    const int lane = threadIdx.x;

    constexpr float RS  = ALPHA / (float)H;
    constexpr float OMA = 1.0f - ALPHA;

    const float so0 = so[0] / (float)H;
    const float so1 = so[1] / (float)H;

    float m0s[8], m1s[8], n0[8], n1[8], wo0s[8], wo1s[8], h[8], r[8];
    float wif[I][8];

#pragma unroll
    for (int k = 0; k < 2; ++k) {
#pragma unroll
        for (int c = 0; c < 4; ++c) {
            const int s = k * 4 + c;
            const int j = 256 * k + 4 * lane + c;
            m0s[s]  = m[2 * j + 0] * RS;
            m1s[s]  = m[2 * j + 1] * RS;
            n0[s]   = n[2 * j + 0];
            n1[s]   = n[2 * j + 1];
            wo0s[s] = wo[2 * j + 0] * so0;
            wo1s[s] = wo[2 * j + 1] * so1;
            h[s]    = h0[j];
            r[s]    = tanhf(h[s]);
#pragma unroll
            for (int i = 0; i < I; ++i) wif[i][s] = wi[i * H + j] * si[i];
        }
    }

    const float* pn    = noise + (size_t)b * T * H + 4 * lane;
    float*       ptraj = traj + (size_t)b * T * H + 4 * lane;
    const float* pin   = input + (size_t)b * T * I;
    float*       pout  = out + (size_t)b * T * O;

    float4 cur0 = *(const float4*)(pn + 0);
    float4 cur1 = *(const float4*)(pn + 256);

    for (int t = 0; t < T; ++t) {
        float4 nxt0, nxt1;
        if (t + 1 < T) {
            nxt0 = *(const float4*)(pn + (size_t)(t + 1) * H);
            nxt1 = *(const float4*)(pn + (size_t)(t + 1) * H + 256);
        }

        float pa0a = 0.f, pa1a = 0.f, po0a = 0.f, po1a = 0.f;
        float pa0b = 0.f, pa1b = 0.f, po0b = 0.f, po1b = 0.f;
#pragma unroll
        for (int s = 0; s < 4; ++s) {
            pa0a = fmaf(r[s], n0[s], pa0a);
            pa1a = fmaf(r[s], n1[s], pa1a);
            po0a = fmaf(r[s], wo0s[s], po0a);
            po1a = fmaf(r[s], wo1s[s], po1a);
            pa0b = fmaf(r[s + 4], n0[s + 4], pa0b);
            pa1b = fmaf(r[s + 4], n1[s + 4], pa1b);
            po0b = fmaf(r[s + 4], wo0s[s + 4], po0b);
            po1b = fmaf(r[s + 4], wo1s[s + 4], po1b);
        }
        float ra0 = wave_sum_to_lane63(pa0a + pa0b);
        float ra1 = wave_sum_to_lane63(pa1a + pa1b);
        float ro0 = wave_sum_to_lane63(po0a + po0b);
        float ro1 = wave_sum_to_lane63(po1a + po1b);

        if (lane == 63 && t > 0) {
            *(float2*)(pout + (size_t)(t - 1) * O) = make_float2(ro0, ro1);
        }

        const float a0 = bcast63(ra0);
        const float a1 = bcast63(ra1);

        float x[I];
#pragma unroll
        for (int i = 0; i < I; ++i) x[i] = pin[(size_t)t * I + i];
        const float nzv[8] = {cur0.x, cur0.y, cur0.z, cur0.w,
                              cur1.x, cur1.y, cur1.z, cur1.w};
        float dv[8];
#pragma unroll
        for (int s = 0; s < 8; ++s) {
            float p = 0.f;
#pragma unroll
            for (int i = 0; i < I; ++i) p = fmaf(x[i], wif[i][s], p);
            dv[s] = fmaf(NOISE_STD, nzv[s], ALPHA * p);
        }

#pragma unroll
        for (int s = 0; s < 8; ++s) {
            float tmp = fmaf(a0, m0s[s], dv[s]);
            tmp       = fmaf(a1, m1s[s], tmp);
            h[s]      = fmaf(h[s], OMA, tmp);
            r[s]      = fast_tanh(h[s]);
        }

        *(float4*)(ptraj + (size_t)t * H + 0)   = make_float4(h[0], h[1], h[2], h[3]);
        *(float4*)(ptraj + (size_t)t * H + 256) = make_float4(h[4], h[5], h[6], h[7]);

        cur0 = nxt0;
        cur1 = nxt1;
    }

    float po0 = 0.f, po1 = 0.f;
#pragma unroll
    for (int s = 0; s < 8; ++s) {
        po0 = fmaf(r[s], wo0s[s], po0);
        po1 = fmaf(r[s], wo1s[s], po1);
    }
    po0 = wave_sum_to_lane63(po0);
    po1 = wave_sum_to_lane63(po1);
    if (lane == 63) {
        *(float2*)(pout + (size_t)(T - 1) * O) = make_float2(po0, po1);
    }
}

// ---------------------------------------------------------------------------
extern "C" void kernel_launch(void* const* d_in, const int* in_sizes, int n_in,
                              void* d_out, int out_size, void* d_ws, size_t ws_size,
                              hipStream_t stream) {
    const float* input = (const float*)d_in[0];
    const float* noise = (const float*)d_in[1];
    const float* wi    = (const float*)d_in[2];
    const float* si    = (const float*)d_in[3];
    const float* m     = (const float*)d_in[4];
    const float* n     = (const float*)d_in[5];
    const float* wo    = (const float*)d_in[6];
    const float* so    = (const float*)d_in[7];
    const float* h0    = (const float*)d_in[8];

    float* out  = (float*)d_out;                       // (B,T,O) first
    float* traj = (float*)d_out + (size_t)B * T * O;   // then (B,T,H)

    const size_t d_bytes = (size_t)B * T * H * sizeof(float);

    if (ws_size >= d_bytes) {
        float* dbuf = (float*)d_ws;
        // 1) precompute d — one block per (b,t) row
        precompute_d_kernel<<<B * T, 128, 0, stream>>>(input, noise, wi, si, dbuf);
        // 2) sequential RNN, 4 waves per batch, outputs deferred
        rnn4_kernel<<<B, 256, 0, stream>>>(dbuf, m, n, h0, traj);
        // 3) outputs from traj (L3-warm), massively parallel
        out_kernel<<<(B * T) / 4, 256, 0, stream>>>(traj, wo, so, out);
    } else {
        // fallback: fully fused single-wave kernel
        rnn_fused_kernel<<<B, 64, 0, stream>>>(noise, input, wi, si,
                                               m, n, wo, so, h0, out, traj);
    }
}

// Round 3
// 560.934 us; speedup vs baseline: 1.0842x; 1.0471x over previous
//
#include <hip/hip_runtime.h>
#include <cstddef>

// Problem constants (match reference)
constexpr int B = 64, T = 1024, I = 8, H = 512, O = 2;
constexpr float ALPHA = 0.2f;
constexpr float NOISE_STD = 0.05f;

// Ring depth for the noise software pipeline (float2 per lane per step).
constexpr int PF = 8;

// ---------------------------------------------------------------------------
// DPP wave-64 sum reduction: result (total of all 64 lanes) lands in lane 63.
// ---------------------------------------------------------------------------
template <int CTRL>
__device__ __forceinline__ float dpp_add(float x) {
    int y = __builtin_amdgcn_update_dpp(0, __float_as_int(x), CTRL, 0xF, 0xF, true);
    return x + __int_as_float(y);
}

__device__ __forceinline__ float wave_sum_to_lane63(float x) {
    x = dpp_add<0x111>(x);  // row_shr:1
    x = dpp_add<0x112>(x);  // row_shr:2
    x = dpp_add<0x114>(x);  // row_shr:4
    x = dpp_add<0x118>(x);  // row_shr:8   -> lane 15 of each row = row sum
    x = dpp_add<0x142>(x);  // row_bcast:15
    x = dpp_add<0x143>(x);  // row_bcast:31 -> lane 63 = full sum
    return x;
}

// Fast tanh: 1 - 2/(exp(2x)+1), via v_exp_f32 + v_rcp_f32.
__device__ __forceinline__ float fast_tanh(float x) {
    float z = __builtin_amdgcn_exp2f(x * 2.885390081777927f);  // e^(2x)
    return fmaf(-2.0f, __builtin_amdgcn_rcpf(z + 1.0f), 1.0f);
}

// ---------------------------------------------------------------------------
// Fully fused RNN: one 256-thread block per batch, 4 waves, wave w owns
// hidden units [w*128, w*128+128), lane l owns units j0 = w*128+2l, j0+1.
//
// Per step, cross-wave combine of the rank-2 partials goes through a
// double-buffered LDS float4 slot with a RAW s_barrier + lgkmcnt(0)-only
// wait. Crucially we never drain vmcnt inside the loop, so the PF-deep
// noise ring-prefetch loads stay in flight across the barrier (the previous
// version used __syncthreads(), whose implicit vmcnt(0) drain put ~450 cyc
// of load latency back on the serial critical path every step).
//
// Race-freedom with ONE barrier/step + double buffer: a write of slot p at
// step t+2 happens after barrier(t+1); every read of slot p at step t
// completed (lgkmcnt-waited) before its wave reached barrier(t+1).
//
// Input projection fused (input[b] staged to LDS once, wif in registers);
// output dots fused (2 extra DPP trees interleave with the 2 a-trees; o
// summed by one lane off the critical path). No workspace, no extra passes.
// ---------------------------------------------------------------------------
__global__ __launch_bounds__(256)
void rnn_fused4_kernel(const float* __restrict__ input,
                       const float* __restrict__ noise,
                       const float* __restrict__ wi,
                       const float* __restrict__ si,
                       const float* __restrict__ m,
                       const float* __restrict__ n,
                       const float* __restrict__ wo,
                       const float* __restrict__ so,
                       const float* __restrict__ h0,
                       float* __restrict__ out,    // (B,T,O)
                       float* __restrict__ traj)   // (B,T,H)
{
    const int b    = blockIdx.x;
    const int w    = threadIdx.x >> 6;
    const int lane = threadIdx.x & 63;
    const int j0   = w * 128 + 2 * lane;   // first of this lane's 2 units

    __shared__ float  xin[T * I];          // 32 KB: input[b], staged once
    __shared__ float4 part[2][4];          // [t&1][wave] = (pa0,pa1,po0,po1)

    // ---- stage input[b] into LDS (coalesced float4) ----
    {
        const float4* src = (const float4*)(input + (size_t)b * T * I);
        float4*       dst = (float4*)xin;
#pragma unroll
        for (int i = 0; i < (T * I / 4) / 256; ++i)
            dst[threadIdx.x + 256 * i] = src[threadIdx.x + 256 * i];
    }
    __syncthreads();   // once, outside the hot loop — vmcnt drain is fine here

    constexpr float RS  = ALPHA / (float)H;
    constexpr float OMA = 1.0f - ALPHA;
    const float so0 = so[0] / (float)H;
    const float so1 = so[1] / (float)H;

    // per-lane coefficients for 2 adjacent units (rows 2j0..2j0+3, 16B aligned)
    const float4 mv = *(const float4*)(m + 2 * j0);
    const float4 nv = *(const float4*)(n + 2 * j0);
    const float4 wv = *(const float4*)(wo + 2 * j0);
    const float mm0[2] = {mv.x * RS, mv.z * RS};
    const float mm1[2] = {mv.y * RS, mv.w * RS};
    const float nn0[2] = {nv.x, nv.z};
    const float nn1[2] = {nv.y, nv.w};
    const float ww0[2] = {wv.x, wv.z};
    const float ww1[2] = {wv.y, wv.w};

    float wif[I][2];
#pragma unroll
    for (int i = 0; i < I; ++i) {
        wif[i][0] = wi[i * H + j0]     * si[i];
        wif[i][1] = wi[i * H + j0 + 1] * si[i];
    }

    const float2 h0v = *(const float2*)(h0 + j0);
    float h[2] = {h0v.x, h0v.y};
    float r[2] = {tanhf(h[0]), tanhf(h[1])};   // full precision, once

    const float* pn   = noise + (size_t)b * T * H + j0;
    float*       pt   = traj  + (size_t)b * T * H + j0;
    float*       pout = out   + (size_t)b * T * O;

    // ---- fill the PF-deep noise register ring (statically indexed) ----
    float2 ring[PF];
#pragma unroll
    for (int u = 0; u < PF; ++u) ring[u] = *(const float2*)(pn + (size_t)u * H);

    static_assert(T % PF == 0, "T must be a multiple of PF");

    for (int tb = 0; tb < T; tb += PF) {
#pragma unroll
        for (int u = 0; u < PF; ++u) {
            const int t = tb + u;

            // uniform broadcast read of this step's 8 input values
            const float4 xa = *(const float4*)(xin + t * I);
            const float4 xb = *(const float4*)(xin + t * I + 4);

            // rank-2 + output partials from current r (4 independent 2-fma chains)
            float pa0 = fmaf(r[1], nn0[1], r[0] * nn0[0]);
            float pa1 = fmaf(r[1], nn1[1], r[0] * nn1[0]);
            float po0 = fmaf(r[1], ww0[1], r[0] * ww0[0]);
            float po1 = fmaf(r[1], ww1[1], r[0] * ww1[0]);

            // consume ring slot u, refill with step t+PF (stays in flight
            // across the raw barrier — no vmcnt drain in this loop)
            const float2 nz = ring[u];
            if (t + PF < T) ring[u] = *(const float2*)(pn + (size_t)(t + PF) * H);

            // 4 interleaved DPP trees (independent -> latency overlaps)
            pa0 = wave_sum_to_lane63(pa0);
            pa1 = wave_sum_to_lane63(pa1);
            po0 = wave_sum_to_lane63(po0);
            po1 = wave_sum_to_lane63(po1);

            // d + (1-a)h, off the post-barrier critical path
            const float x0 = xa.x, x1 = xa.y, x2 = xa.z, x3 = xa.w;
            const float x4 = xb.x, x5 = xb.y, x6 = xb.z, x7 = xb.w;
            float acc0 = x0 * wif[0][0], acc1 = x0 * wif[0][1];
            acc0 = fmaf(x1, wif[1][0], acc0); acc1 = fmaf(x1, wif[1][1], acc1);
            acc0 = fmaf(x2, wif[2][0], acc0); acc1 = fmaf(x2, wif[2][1], acc1);
            acc0 = fmaf(x3, wif[3][0], acc0); acc1 = fmaf(x3, wif[3][1], acc1);
            acc0 = fmaf(x4, wif[4][0], acc0); acc1 = fmaf(x4, wif[4][1], acc1);
            acc0 = fmaf(x5, wif[5][0], acc0); acc1 = fmaf(x5, wif[5][1], acc1);
            acc0 = fmaf(x6, wif[6][0], acc0); acc1 = fmaf(x6, wif[6][1], acc1);
            acc0 = fmaf(x7, wif[7][0], acc0); acc1 = fmaf(x7, wif[7][1], acc1);
            const float dv0 = fmaf(NOISE_STD, nz.x, ALPHA * acc0);
            const float dv1 = fmaf(NOISE_STD, nz.y, ALPHA * acc1);
            const float pre0 = fmaf(h[0], OMA, dv0);
            const float pre1 = fmaf(h[1], OMA, dv1);

            if (lane == 63) part[t & 1][w] = make_float4(pa0, pa1, po0, po1);

            // raw barrier: LDS-visibility wait ONLY (no vmcnt drain)
            __builtin_amdgcn_sched_barrier(0);
            asm volatile("s_waitcnt lgkmcnt(0)" ::: "memory");
            __builtin_amdgcn_s_barrier();
            __builtin_amdgcn_sched_barrier(0);

            // broadcast-read the 4 wave partials
            const float4 q0 = part[t & 1][0];
            const float4 q1 = part[t & 1][1];
            const float4 q2 = part[t & 1][2];
            const float4 q3 = part[t & 1][3];
            const float a0 = (q0.x + q1.x) + (q2.x + q3.x);
            const float a1 = (q0.y + q1.y) + (q2.y + q3.y);

            // out[t-1] from the pre-update r (matches reference indexing);
            // single-lane, off the critical path
            if (t > 0 && threadIdx.x == 63) {
                const float o0 = (q0.z + q1.z) + (q2.z + q3.z);
                const float o1 = (q0.w + q1.w) + (q2.w + q3.w);
                *(float2*)(pout + (size_t)(t - 1) * O) =
                    make_float2(o0 * so0, o1 * so1);
            }

            // state update + fast tanh (critical path: 2 fma + tanh)
            h[0] = fmaf(a1, mm1[0], fmaf(a0, mm0[0], pre0));
            h[1] = fmaf(a1, mm1[1], fmaf(a0, mm0[1], pre1));
            r[0] = fast_tanh(h[0]);
            r[1] = fast_tanh(h[1]);

            *(float2*)(pt + (size_t)t * H) = make_float2(h[0], h[1]);
        }
    }

    // ---- final output for t = T-1 (uses post-update r) ----
    {
        float po0 = fmaf(r[1], ww0[1], r[0] * ww0[0]);
        float po1 = fmaf(r[1], ww1[1], r[0] * ww1[0]);
        po0 = wave_sum_to_lane63(po0);
        po1 = wave_sum_to_lane63(po1);
        // Safe to reuse part[0]: every read of part[0] (last at t=T-2)
        // completed before barrier(T-1), which precedes this write.
        if (lane == 63) part[0][w] = make_float4(po0, po1, 0.f, 0.f);
        __syncthreads();
        if (threadIdx.x == 0) {
            const float4 q0 = part[0][0];
            const float4 q1 = part[0][1];
            const float4 q2 = part[0][2];
            const float4 q3 = part[0][3];
            const float o0 = (q0.x + q1.x) + (q2.x + q3.x);
            const float o1 = (q0.y + q1.y) + (q2.y + q3.y);
            *(float2*)(pout + (size_t)(T - 1) * O) =
                make_float2(o0 * so0, o1 * so1);
        }
    }
}

// ---------------------------------------------------------------------------
extern "C" void kernel_launch(void* const* d_in, const int* in_sizes, int n_in,
                              void* d_out, int out_size, void* d_ws, size_t ws_size,
                              hipStream_t stream) {
    const float* input = (const float*)d_in[0];
    const float* noise = (const float*)d_in[1];
    const float* wi    = (const float*)d_in[2];
    const float* si    = (const float*)d_in[3];
    const float* m     = (const float*)d_in[4];
    const float* n     = (const float*)d_in[5];
    const float* wo    = (const float*)d_in[6];
    const float* so    = (const float*)d_in[7];
    const float* h0    = (const float*)d_in[8];

    float* out  = (float*)d_out;                       // (B,T,O) first
    float* traj = (float*)d_out + (size_t)B * T * O;   // then (B,T,H)

    (void)d_ws; (void)ws_size;

    // Single fully fused kernel: 64 blocks x 256 threads (4 waves/batch).
    rnn_fused4_kernel<<<B, 256, 0, stream>>>(input, noise, wi, si,
                                             m, n, wo, so, h0, out, traj);
}